// Round 16
// baseline (385.179 us; speedup 1.0000x reference)
//
#include <hip/hip_runtime.h>
#include <hip/hip_bf16.h>
#include <hip/hip_fp16.h>

// GraphConv: out = relu(A_hat @ (X @ W) + b)
// N=100000, E=3200000, F=C=256, fp32 in/out.
//
// Round 16 = round 15 with the GEMM split across two dispatches so the
// per-bucket sort hides under gemm tail (sort was 20us serial on the
// critical path):
//   k_pre -> kD1 (bin 391 || gemm tiles [0,G1)) ->
//   kD2 (sort 1563 || gemm tiles [G1,1563)) -> k_agg
// All compute bodies byte-identical to round 15 (clean A/B; only dispatch
// packing changed). Agg pinned at ~231us = 751MB @ ~3.8TB/s L2-miss fill
// (rounds 5-8: MLP/width/blocking insensitive; fp8-H rejected on error
// budget ~0.7 > 0.4175 threshold).

#define CAP 2432
#define NBMAX 1600
#define CH_A3 8192
#define D1_SMEM 19200
#define D2_SMEM 20992
#define G1SPLIT 1000

typedef __attribute__((ext_vector_type(4))) float f32x4;
typedef __attribute__((ext_vector_type(8))) short s16x8;

__device__ __forceinline__ unsigned short f2bf(float f) {
    unsigned u = __float_as_uint(f);
    u += 0x7FFFu + ((u >> 16) & 1u);   // RNE
    return (unsigned short)(u >> 16);
}
__device__ __forceinline__ float bf2f(unsigned short s) {
    return __uint_as_float(((unsigned)s) << 16);
}

// ---------------- k_pre: Wt[c][k] = bf16(W[k][c]); zero gcur ----------------
__global__ __launch_bounds__(256) void k_pre(const float* __restrict__ W,
                                             unsigned short* __restrict__ Wt,
                                             int* __restrict__ gcur, int NB) {
    int bid = blockIdx.x, t = threadIdx.x;
    if (bid < 256) {
        int idx = bid * 256 + t;        // 65536 elems
        int k = idx >> 8, c = idx & 255;
        Wt[c * 256 + k] = f2bf(W[idx]);
    } else {
        for (int j = t; j < NB; j += 256) gcur[j] = 0;
    }
}

// ---------------- A3: bin edges into fixed-capacity buckets -----------------
// One packed int2 {cv, lr} scattered write per edge.
__device__ __forceinline__ void a3_body(const int* __restrict__ row,
                                        const int* __restrict__ col,
                                        const float* __restrict__ val,
                                        int* __restrict__ gcur,
                                        int2* __restrict__ bin8,
                                        int E, int NB, int chunk, char* smem) {
    int* h    = (int*)smem;         // NB
    int* base = h + NBMAX;          // NB
    int* cur  = base + NBMAX;       // NB
    int t = threadIdx.x;
    for (int j = t; j < NB; j += 256) { h[j] = 0; cur[j] = 0; }
    __syncthreads();
    int start = chunk * CH_A3;
    int end = min(E, start + CH_A3);
    for (int i = start + t; i < end; i += 256)
        atomicAdd(&h[row[i] >> 6], 1);
    __syncthreads();
    for (int j = t; j < NB; j += 256) {
        int c = h[j];
        base[j] = c ? atomicAdd(&gcur[j], c) : 0;
    }
    __syncthreads();
    for (int i = start + t; i < end; i += 256) {
        int r = row[i];
        int b = r >> 6;
        int ofs = atomicAdd(&cur[b], 1);
        unsigned hb = (unsigned)__half_as_ushort(__float2half(val[i]));  // sign=0
        bin8[(size_t)b * CAP + base[b] + ofs] =
            make_int2((int)((unsigned)col[i] | (hb << 17)), r & 63);
    }
}

// ---------------- MFMA GEMM tile body (round-9, verified) -------------------
// Block g: rows [g*64, g*64+64) x all 256 cols. 4 waves: wave w owns cols
// [w*64, w*64+64) -> acc[4][4] frags of 16x16x32, fp32 accum. X cast to bf16
// in-register during LDS staging, read once (NT). B frags from Wt (L2-hot).
__device__ __forceinline__ void gemm_body(const float* __restrict__ X,
                                          const unsigned short* __restrict__ Wt,
                                          unsigned short* __restrict__ H,
                                          int M, int g, char* smem) {
    typedef unsigned short AsRow[40];
    AsRow* As = (AsRow*)smem;
    int t = threadIdx.x;
    int lane = t & 63;
    int w = t >> 6;
    int r0 = g * 64;
    int c0 = w * 64;
    int srow = t >> 2;
    int sslot = t & 3;
    int gr = r0 + srow; if (gr >= M) gr = M - 1;

    f32x4 acc[4][4] = {};

    for (int k0 = 0; k0 < 256; k0 += 32) {
        const float* p = &X[(size_t)gr * 256 + k0 + sslot * 8];
        f32x4 a0 = __builtin_nontemporal_load((const f32x4*)p);
        f32x4 a1 = __builtin_nontemporal_load((const f32x4*)(p + 4));
        s16x8 va;
        va[0] = (short)f2bf(a0[0]); va[1] = (short)f2bf(a0[1]);
        va[2] = (short)f2bf(a0[2]); va[3] = (short)f2bf(a0[3]);
        va[4] = (short)f2bf(a1[0]); va[5] = (short)f2bf(a1[1]);
        va[6] = (short)f2bf(a1[2]); va[7] = (short)f2bf(a1[3]);
        __syncthreads();
        *(s16x8*)&As[srow][sslot * 8] = va;
        __syncthreads();

        int kofs = (lane >> 4) * 8;
        s16x8 afr[4], bfr[4];
#pragma unroll
        for (int mi = 0; mi < 4; ++mi)
            afr[mi] = *(const s16x8*)&As[mi * 16 + (lane & 15)][kofs];
#pragma unroll
        for (int ni = 0; ni < 4; ++ni) {
            int cn = c0 + ni * 16 + (lane & 15);
            bfr[ni] = *(const s16x8*)&Wt[(size_t)cn * 256 + k0 + kofs];
        }
#pragma unroll
        for (int mi = 0; mi < 4; ++mi)
#pragma unroll
            for (int ni = 0; ni < 4; ++ni)
                acc[mi][ni] = __builtin_amdgcn_mfma_f32_16x16x32_bf16(
                    afr[mi], bfr[ni], acc[mi][ni], 0, 0, 0);
    }

    // C write: col = lane&15, row = (lane>>4)*4 + j  [m89-verified layout]
#pragma unroll
    for (int mi = 0; mi < 4; ++mi) {
#pragma unroll
        for (int ni = 0; ni < 4; ++ni) {
            int rg = r0 + mi * 16 + (lane >> 4) * 4;
            int cg = c0 + ni * 16 + (lane & 15);
#pragma unroll
            for (int j = 0; j < 4; ++j) {
                if (rg + j < M)
                    H[(size_t)(rg + j) * 256 + cg] = f2bf(acc[mi][ni][j]);
            }
        }
    }
}

// ---------------- kB2 sort body (round-15 logic, extern smem) ---------------
// Block b: stage its <=CAP int2 edges into LDS (single global read), per-wave
// privatized histogram, 64-bin scan, write sorted cv (4B) back into the FIRST
// HALF of its own bucket window (full stage before scatter -> safe).
// rowinfo[node] = {global uint index of row start, count}.
__device__ __forceinline__ void kb2_body(int2* __restrict__ bin8,
                                         const int* __restrict__ gcur,
                                         int2* __restrict__ rowinfo,
                                         int N, int b, char* smem) {
    int2* se  = (int2*)smem;            // CAP (8B aligned, first)
    int* hist = (int*)(se + CAP);       // 4*64
    int* rs   = hist + 256;             // 64
    int* cnt  = rs + 64;                // 64
    int t = threadIdx.x;
    int w = t >> 6;
    size_t gb = (size_t)b * CAP;
    int n = gcur[b];

    if (t < 64) { hist[0*64+t] = 0; hist[1*64+t] = 0; hist[2*64+t] = 0; hist[3*64+t] = 0; }
    __syncthreads();
    for (int i = t; i < n; i += 256) {
        int2 e = bin8[gb + i];
        se[i] = e;
        atomicAdd(&hist[w*64 + e.y], 1);
    }
    __syncthreads();
    if (t < 64) {
        int h0 = hist[0*64+t], h1 = hist[1*64+t], h2 = hist[2*64+t], h3 = hist[3*64+t];
        cnt[t] = h0 + h1 + h2 + h3;
        rs[t] = cnt[t];
        hist[0*64+t] = 0;
        hist[1*64+t] = h0;
        hist[2*64+t] = h0 + h1;
        hist[3*64+t] = h0 + h1 + h2;
    }
    __syncthreads();
    for (int off = 1; off < 64; off <<= 1) {
        int v = (t < 64 && t >= off) ? rs[t - off] : 0;
        __syncthreads();
        if (t < 64 && t >= off) rs[t] += v;
        __syncthreads();
    }
    unsigned* cvout = (unsigned*)&bin8[gb];      // own window, first half
    if (t < 64) {
        int st = rs[t] - cnt[t];
        hist[0*64+t] += st; hist[1*64+t] += st;
        hist[2*64+t] += st; hist[3*64+t] += st;
        int node = b * 64 + t;
        if (node < N) rowinfo[node] = make_int2((int)(gb * 2 + st), cnt[t]);
    }
    __syncthreads();
    for (int i = t; i < n; i += 256) {
        int2 e = se[i];
        int pos = atomicAdd(&hist[w*64 + e.y], 1);
        cvout[pos] = (unsigned)e.x;
    }
}

// ---------------- D1: binning || gemm tiles [0, G1) -------------------------
__global__ __launch_bounds__(256) void kD1(const int* __restrict__ row,
                                           const int* __restrict__ col,
                                           const float* __restrict__ val,
                                           int* __restrict__ gcur,
                                           int2* __restrict__ bin8,
                                           int E, int NB, int nA3,
                                           const float* __restrict__ X,
                                           const unsigned short* __restrict__ Wt,
                                           unsigned short* __restrict__ H, int M) {
    extern __shared__ char smem[];
    int bid = blockIdx.x;
    if (bid < nA3) {
        a3_body(row, col, val, gcur, bin8, E, NB, bid, smem);
        return;
    }
    gemm_body(X, Wt, H, M, bid - nA3, smem);
}

// ---------------- D2: sort || gemm tiles [G1, 1563) -------------------------
__global__ __launch_bounds__(256) void kD2(int2* __restrict__ bin8,
                                           const int* __restrict__ gcur,
                                           int2* __restrict__ rowinfo,
                                           int N, int NB,
                                           const float* __restrict__ X,
                                           const unsigned short* __restrict__ Wt,
                                           unsigned short* __restrict__ H,
                                           int M, int g0) {
    extern __shared__ char smem[];
    int bid = blockIdx.x;
    if (bid < NB) {
        kb2_body(bin8, gcur, rowinfo, N, bid, smem);
        return;
    }
    gemm_body(X, Wt, H, M, g0 + (bid - NB), smem);
}

// ---------------- aggregation (round-5 pinned form) --------------------------
// Wave per node. lane = 8 channels (16B gathers); lane-half h processes edge
// i+h -> 2 edges per load instr, 8 edges in flight. Cross-half combine via
// shfl_xor(32). Fused bias + relu. Plain store.
__global__ __launch_bounds__(256) void k_agg(const unsigned short* __restrict__ H,
                                             const int2* __restrict__ rowinfo,
                                             const unsigned* __restrict__ csr,
                                             const float* __restrict__ bias,
                                             float* __restrict__ out, int n) {
    int wave = threadIdx.x >> 6;
    int lane = threadIdx.x & 63;
    int node = blockIdx.x * 4 + wave;
    if (node >= n) return;
    int2 ri = rowinfo[node];
    int s = ri.x;
    int e = ri.x + ri.y;
    int h = lane >> 5;
    int cbase = (lane & 31) * 8;

    float a0=0.f,a1=0.f,a2=0.f,a3=0.f,a4=0.f,a5=0.f,a6=0.f,a7=0.f;

#define ACC(K, HV)                                                      \
    {                                                                   \
        float v = __half2float(__ushort_as_half((unsigned short)((K) >> 17))); \
        a0 += v * bf2f((unsigned short)(HV)[0]);                        \
        a1 += v * bf2f((unsigned short)(HV)[1]);                        \
        a2 += v * bf2f((unsigned short)(HV)[2]);                        \
        a3 += v * bf2f((unsigned short)(HV)[3]);                        \
        a4 += v * bf2f((unsigned short)(HV)[4]);                        \
        a5 += v * bf2f((unsigned short)(HV)[5]);                        \
        a6 += v * bf2f((unsigned short)(HV)[6]);                        \
        a7 += v * bf2f((unsigned short)(HV)[7]);                        \
    }

    int i = s;
    for (; i + 7 < e; i += 8) {
        unsigned k0 = csr[i + h];
        unsigned k1 = csr[i + 2 + h];
        unsigned k2 = csr[i + 4 + h];
        unsigned k3 = csr[i + 6 + h];
        s16x8 g0 = *(const s16x8*)&H[(k0 & 0x1FFFFu) * 256 + cbase];
        s16x8 g1 = *(const s16x8*)&H[(k1 & 0x1FFFFu) * 256 + cbase];
        s16x8 g2 = *(const s16x8*)&H[(k2 & 0x1FFFFu) * 256 + cbase];
        s16x8 g3 = *(const s16x8*)&H[(k3 & 0x1FFFFu) * 256 + cbase];
        ACC(k0, g0); ACC(k1, g1); ACC(k2, g2); ACC(k3, g3);
    }
    for (; i + 1 < e; i += 2) {
        unsigned k0 = csr[i + h];
        s16x8 g0 = *(const s16x8*)&H[(k0 & 0x1FFFFu) * 256 + cbase];
        ACC(k0, g0);
    }
    if (i < e) {
        // odd tail: both halves gather same row; hi half contributes 0
        unsigned k0 = csr[i];
        s16x8 g0 = *(const s16x8*)&H[(k0 & 0x1FFFFu) * 256 + cbase];
        float v = h ? 0.f
                    : __half2float(__ushort_as_half((unsigned short)(k0 >> 17)));
        a0 += v * bf2f((unsigned short)g0[0]);
        a1 += v * bf2f((unsigned short)g0[1]);
        a2 += v * bf2f((unsigned short)g0[2]);
        a3 += v * bf2f((unsigned short)g0[3]);
        a4 += v * bf2f((unsigned short)g0[4]);
        a5 += v * bf2f((unsigned short)g0[5]);
        a6 += v * bf2f((unsigned short)g0[6]);
        a7 += v * bf2f((unsigned short)g0[7]);
    }
#undef ACC

    a0 += __shfl_xor(a0, 32); a1 += __shfl_xor(a1, 32);
    a2 += __shfl_xor(a2, 32); a3 += __shfl_xor(a3, 32);
    a4 += __shfl_xor(a4, 32); a5 += __shfl_xor(a5, 32);
    a6 += __shfl_xor(a6, 32); a7 += __shfl_xor(a7, 32);

    float w0 = h ? a4 : a0;
    float w1 = h ? a5 : a1;
    float w2 = h ? a6 : a2;
    float w3 = h ? a7 : a3;
    int cw = cbase + h * 4;
    float4 b4 = *(const float4*)&bias[cw];
    float4 o;
    o.x = fmaxf(w0 + b4.x, 0.f);
    o.y = fmaxf(w1 + b4.y, 0.f);
    o.z = fmaxf(w2 + b4.z, 0.f);
    o.w = fmaxf(w3 + b4.w, 0.f);
    *(float4*)&out[(size_t)node * 256 + cw] = o;
}

extern "C" void kernel_launch(void* const* d_in, const int* in_sizes, int n_in,
                              void* d_out, int out_size, void* d_ws, size_t ws_size,
                              hipStream_t stream) {
    const float* x     = (const float*)d_in[0];
    const int*   erow  = (const int*)d_in[1];
    const int*   ecol  = (const int*)d_in[2];
    const float* evals = (const float*)d_in[3];
    const float* W     = (const float*)d_in[4];
    const float* bias  = (const float*)d_in[5];
    float* out = (float*)d_out;

    const int C = 256;
    const int N = in_sizes[0] / C;        // 100000
    const int E = in_sizes[1];            // 3200000
    const int NB = (N + 63) / 64;         // 1563 buckets of 64 rows

    // Workspace carve (256B aligned): 51.2 + 0.13 + 0.01 + 0.8 + 30.4 ~ 82.6MB
    // (proven fits in rounds 12-15).
    char* ws = (char*)d_ws;
    size_t off = 0;
    auto carve = [&](size_t bytes) -> void* {
        void* p = ws + off;
        off += (bytes + 255) & ~(size_t)255;
        return p;
    };
    unsigned short* Hbf = (unsigned short*)carve((size_t)N * C * 2);   // 51.2MB
    unsigned short* Wt  = (unsigned short*)carve((size_t)C * 256 * 2); // 0.13MB
    int*            gcur= (int*)carve((size_t)NB * 4);
    int2*           rinf= (int2*)carve((size_t)N * 8);                 // 0.8MB
    int2*           bin8= (int2*)carve((size_t)NB * CAP * 8);          // 30.4MB

    int nA3 = (E + CH_A3 - 1) / CH_A3;    // 391
    int gemmBlocks = (N + 63) / 64;       // 1563
    int G1 = G1SPLIT;                     // gemm tiles in kD1
    int G2 = gemmBlocks - G1;             // gemm tiles in kD2

    k_pre<<<257, 256, 0, stream>>>(W, Wt, gcur, NB);
    kD1<<<nA3 + G1, 256, D1_SMEM, stream>>>(erow, ecol, evals, gcur,
                                            bin8, E, NB, nA3,
                                            x, Wt, Hbf, N);
    kD2<<<NB + G2, 256, D2_SMEM, stream>>>(bin8, gcur, rinf, N, NB,
                                           x, Wt, Hbf, N, G1);
    k_agg<<<(N + 3) / 4, 256, 0, stream>>>(Hbf, rinf, (unsigned*)bin8, bias, out, N);
}

// Round 17
// 363.723 us; speedup vs baseline: 1.0590x; 1.0590x over previous
//
#include <hip/hip_runtime.h>
#include <hip/hip_bf16.h>
#include <hip/hip_fp16.h>

// GraphConv: out = relu(A_hat @ (X @ W) + b)
// N=100000, E=3200000, F=C=256, fp32 in/out.
//
// Round 17 = byte-identical revert to round 15 (session best, 362us).
// Round 16's sort||gemm split regressed (-23us): 21KB LDS capped kD2 at 7
// blocks/CU (gemm tiles ran at 8 in round 15's packing) + second dispatch
// ramp/drain tail. Front half is at its dependency-packing limit.
//
// State: k_agg pinned at ~231us = 751MB FETCH @ ~3.8TB/s L2-miss fill
// (rounds 5-8: width/MLP/blocking/NT insensitive). fp8-H rejected on error
// budget (~0.5-0.7 > 0.4175 threshold). Front half ~130us vs ~40us traffic
// floor, already bin||gemm overlapped; round-12/16 probes show packing
// changes trade noise.
//
// Pipeline: k_pre -> kD1 (bin || gemm) -> kB2 (sort) -> k_agg.

#define CAP 2432
#define NBMAX 1600
#define CH_A3 8192
#define D1_SMEM 19200

typedef __attribute__((ext_vector_type(4))) float f32x4;
typedef __attribute__((ext_vector_type(8))) short s16x8;

__device__ __forceinline__ unsigned short f2bf(float f) {
    unsigned u = __float_as_uint(f);
    u += 0x7FFFu + ((u >> 16) & 1u);   // RNE
    return (unsigned short)(u >> 16);
}
__device__ __forceinline__ float bf2f(unsigned short s) {
    return __uint_as_float(((unsigned)s) << 16);
}

// ---------------- k_pre: Wt[c][k] = bf16(W[k][c]); zero gcur ----------------
__global__ __launch_bounds__(256) void k_pre(const float* __restrict__ W,
                                             unsigned short* __restrict__ Wt,
                                             int* __restrict__ gcur, int NB) {
    int bid = blockIdx.x, t = threadIdx.x;
    if (bid < 256) {
        int idx = bid * 256 + t;        // 65536 elems
        int k = idx >> 8, c = idx & 255;
        Wt[c * 256 + k] = f2bf(W[idx]);
    } else {
        for (int j = t; j < NB; j += 256) gcur[j] = 0;
    }
}

// ---------------- A3: bin edges into fixed-capacity buckets -----------------
// One packed int2 {cv, lr} scattered write per edge.
__device__ __forceinline__ void a3_body(const int* __restrict__ row,
                                        const int* __restrict__ col,
                                        const float* __restrict__ val,
                                        int* __restrict__ gcur,
                                        int2* __restrict__ bin8,
                                        int E, int NB, int chunk, char* smem) {
    int* h    = (int*)smem;         // NB
    int* base = h + NBMAX;          // NB
    int* cur  = base + NBMAX;       // NB
    int t = threadIdx.x;
    for (int j = t; j < NB; j += 256) { h[j] = 0; cur[j] = 0; }
    __syncthreads();
    int start = chunk * CH_A3;
    int end = min(E, start + CH_A3);
    for (int i = start + t; i < end; i += 256)
        atomicAdd(&h[row[i] >> 6], 1);
    __syncthreads();
    for (int j = t; j < NB; j += 256) {
        int c = h[j];
        base[j] = c ? atomicAdd(&gcur[j], c) : 0;
    }
    __syncthreads();
    for (int i = start + t; i < end; i += 256) {
        int r = row[i];
        int b = r >> 6;
        int ofs = atomicAdd(&cur[b], 1);
        unsigned hb = (unsigned)__half_as_ushort(__float2half(val[i]));  // sign=0
        bin8[(size_t)b * CAP + base[b] + ofs] =
            make_int2((int)((unsigned)col[i] | (hb << 17)), r & 63);
    }
}

// ---------------- MFMA GEMM tile body (round-9, verified) -------------------
// Block g: rows [g*64, g*64+64) x all 256 cols. 4 waves: wave w owns cols
// [w*64, w*64+64) -> acc[4][4] frags of 16x16x32, fp32 accum. X cast to bf16
// in-register during LDS staging, read once (NT). B frags from Wt (L2-hot).
__device__ __forceinline__ void gemm_body(const float* __restrict__ X,
                                          const unsigned short* __restrict__ Wt,
                                          unsigned short* __restrict__ H,
                                          int M, int g, char* smem) {
    typedef unsigned short AsRow[40];
    AsRow* As = (AsRow*)smem;
    int t = threadIdx.x;
    int lane = t & 63;
    int w = t >> 6;
    int r0 = g * 64;
    int c0 = w * 64;
    int srow = t >> 2;
    int sslot = t & 3;
    int gr = r0 + srow; if (gr >= M) gr = M - 1;

    f32x4 acc[4][4] = {};

    for (int k0 = 0; k0 < 256; k0 += 32) {
        const float* p = &X[(size_t)gr * 256 + k0 + sslot * 8];
        f32x4 a0 = __builtin_nontemporal_load((const f32x4*)p);
        f32x4 a1 = __builtin_nontemporal_load((const f32x4*)(p + 4));
        s16x8 va;
        va[0] = (short)f2bf(a0[0]); va[1] = (short)f2bf(a0[1]);
        va[2] = (short)f2bf(a0[2]); va[3] = (short)f2bf(a0[3]);
        va[4] = (short)f2bf(a1[0]); va[5] = (short)f2bf(a1[1]);
        va[6] = (short)f2bf(a1[2]); va[7] = (short)f2bf(a1[3]);
        __syncthreads();
        *(s16x8*)&As[srow][sslot * 8] = va;
        __syncthreads();

        int kofs = (lane >> 4) * 8;
        s16x8 afr[4], bfr[4];
#pragma unroll
        for (int mi = 0; mi < 4; ++mi)
            afr[mi] = *(const s16x8*)&As[mi * 16 + (lane & 15)][kofs];
#pragma unroll
        for (int ni = 0; ni < 4; ++ni) {
            int cn = c0 + ni * 16 + (lane & 15);
            bfr[ni] = *(const s16x8*)&Wt[(size_t)cn * 256 + k0 + kofs];
        }
#pragma unroll
        for (int mi = 0; mi < 4; ++mi)
#pragma unroll
            for (int ni = 0; ni < 4; ++ni)
                acc[mi][ni] = __builtin_amdgcn_mfma_f32_16x16x32_bf16(
                    afr[mi], bfr[ni], acc[mi][ni], 0, 0, 0);
    }

    // C write: col = lane&15, row = (lane>>4)*4 + j  [m89-verified layout]
#pragma unroll
    for (int mi = 0; mi < 4; ++mi) {
#pragma unroll
        for (int ni = 0; ni < 4; ++ni) {
            int rg = r0 + mi * 16 + (lane >> 4) * 4;
            int cg = c0 + ni * 16 + (lane & 15);
#pragma unroll
            for (int j = 0; j < 4; ++j) {
                if (rg + j < M)
                    H[(size_t)(rg + j) * 256 + cg] = f2bf(acc[mi][ni][j]);
            }
        }
    }
}

// ---------------- D1: binning || GEMM ---------------------------------------
__global__ __launch_bounds__(256) void kD1(const int* __restrict__ row,
                                           const int* __restrict__ col,
                                           const float* __restrict__ val,
                                           int* __restrict__ gcur,
                                           int2* __restrict__ bin8,
                                           int E, int NB, int nA3,
                                           const float* __restrict__ X,
                                           const unsigned short* __restrict__ Wt,
                                           unsigned short* __restrict__ H, int M) {
    extern __shared__ char smem[];
    int bid = blockIdx.x;
    if (bid < nA3) {
        a3_body(row, col, val, gcur, bin8, E, NB, bid, smem);
        return;
    }
    gemm_body(X, Wt, H, M, bid - nA3, smem);
}

// ---------------- kB2: per-bucket counting sort ------------------------------
// Block b: stage its <=CAP int2 edges into LDS (single global read), per-wave
// privatized histogram, 64-bin scan, write sorted cv (4B) back into the FIRST
// HALF of its own bucket window (full stage before scatter -> safe).
// rowinfo[node] = {global uint index of row start, count}.
__global__ __launch_bounds__(256) void kB2(int2* __restrict__ bin8,
                                           const int* __restrict__ gcur,
                                           int2* __restrict__ rowinfo, int N) {
    __shared__ int2 se[CAP];
    __shared__ int hist[4][64];
    __shared__ int rs[64], cnt[64];
    int b = blockIdx.x;
    int t = threadIdx.x;
    int w = t >> 6;
    size_t gb = (size_t)b * CAP;
    int n = gcur[b];

    if (t < 64) { hist[0][t] = 0; hist[1][t] = 0; hist[2][t] = 0; hist[3][t] = 0; }
    __syncthreads();
    for (int i = t; i < n; i += 256) {
        int2 e = bin8[gb + i];
        se[i] = e;
        atomicAdd(&hist[w][e.y], 1);
    }
    __syncthreads();
    if (t < 64) {
        int h0 = hist[0][t], h1 = hist[1][t], h2 = hist[2][t], h3 = hist[3][t];
        cnt[t] = h0 + h1 + h2 + h3;
        rs[t] = cnt[t];
        hist[0][t] = 0;
        hist[1][t] = h0;
        hist[2][t] = h0 + h1;
        hist[3][t] = h0 + h1 + h2;
    }
    __syncthreads();
    for (int off = 1; off < 64; off <<= 1) {
        int v = (t < 64 && t >= off) ? rs[t - off] : 0;
        __syncthreads();
        if (t < 64 && t >= off) rs[t] += v;
        __syncthreads();
    }
    unsigned* cvout = (unsigned*)&bin8[gb];      // own window, first half
    if (t < 64) {
        int st = rs[t] - cnt[t];
        hist[0][t] += st; hist[1][t] += st;
        hist[2][t] += st; hist[3][t] += st;
        int node = b * 64 + t;
        if (node < N) rowinfo[node] = make_int2((int)(gb * 2 + st), cnt[t]);
    }
    __syncthreads();
    for (int i = t; i < n; i += 256) {
        int2 e = se[i];
        int pos = atomicAdd(&hist[w][e.y], 1);
        cvout[pos] = (unsigned)e.x;
    }
}

// ---------------- aggregation (round-5 pinned form) --------------------------
// Wave per node. lane = 8 channels (16B gathers); lane-half h processes edge
// i+h -> 2 edges per load instr, 8 edges in flight. Cross-half combine via
// shfl_xor(32). Fused bias + relu. Plain store.
__global__ __launch_bounds__(256) void k_agg(const unsigned short* __restrict__ H,
                                             const int2* __restrict__ rowinfo,
                                             const unsigned* __restrict__ csr,
                                             const float* __restrict__ bias,
                                             float* __restrict__ out, int n) {
    int wave = threadIdx.x >> 6;
    int lane = threadIdx.x & 63;
    int node = blockIdx.x * 4 + wave;
    if (node >= n) return;
    int2 ri = rowinfo[node];
    int s = ri.x;
    int e = ri.x + ri.y;
    int h = lane >> 5;
    int cbase = (lane & 31) * 8;

    float a0=0.f,a1=0.f,a2=0.f,a3=0.f,a4=0.f,a5=0.f,a6=0.f,a7=0.f;

#define ACC(K, HV)                                                      \
    {                                                                   \
        float v = __half2float(__ushort_as_half((unsigned short)((K) >> 17))); \
        a0 += v * bf2f((unsigned short)(HV)[0]);                        \
        a1 += v * bf2f((unsigned short)(HV)[1]);                        \
        a2 += v * bf2f((unsigned short)(HV)[2]);                        \
        a3 += v * bf2f((unsigned short)(HV)[3]);                        \
        a4 += v * bf2f((unsigned short)(HV)[4]);                        \
        a5 += v * bf2f((unsigned short)(HV)[5]);                        \
        a6 += v * bf2f((unsigned short)(HV)[6]);                        \
        a7 += v * bf2f((unsigned short)(HV)[7]);                        \
    }

    int i = s;
    for (; i + 7 < e; i += 8) {
        unsigned k0 = csr[i + h];
        unsigned k1 = csr[i + 2 + h];
        unsigned k2 = csr[i + 4 + h];
        unsigned k3 = csr[i + 6 + h];
        s16x8 g0 = *(const s16x8*)&H[(k0 & 0x1FFFFu) * 256 + cbase];
        s16x8 g1 = *(const s16x8*)&H[(k1 & 0x1FFFFu) * 256 + cbase];
        s16x8 g2 = *(const s16x8*)&H[(k2 & 0x1FFFFu) * 256 + cbase];
        s16x8 g3 = *(const s16x8*)&H[(k3 & 0x1FFFFu) * 256 + cbase];
        ACC(k0, g0); ACC(k1, g1); ACC(k2, g2); ACC(k3, g3);
    }
    for (; i + 1 < e; i += 2) {
        unsigned k0 = csr[i + h];
        s16x8 g0 = *(const s16x8*)&H[(k0 & 0x1FFFFu) * 256 + cbase];
        ACC(k0, g0);
    }
    if (i < e) {
        // odd tail: both halves gather same row; hi half contributes 0
        unsigned k0 = csr[i];
        s16x8 g0 = *(const s16x8*)&H[(k0 & 0x1FFFFu) * 256 + cbase];
        float v = h ? 0.f
                    : __half2float(__ushort_as_half((unsigned short)(k0 >> 17)));
        a0 += v * bf2f((unsigned short)g0[0]);
        a1 += v * bf2f((unsigned short)g0[1]);
        a2 += v * bf2f((unsigned short)g0[2]);
        a3 += v * bf2f((unsigned short)g0[3]);
        a4 += v * bf2f((unsigned short)g0[4]);
        a5 += v * bf2f((unsigned short)g0[5]);
        a6 += v * bf2f((unsigned short)g0[6]);
        a7 += v * bf2f((unsigned short)g0[7]);
    }
#undef ACC

    a0 += __shfl_xor(a0, 32); a1 += __shfl_xor(a1, 32);
    a2 += __shfl_xor(a2, 32); a3 += __shfl_xor(a3, 32);
    a4 += __shfl_xor(a4, 32); a5 += __shfl_xor(a5, 32);
    a6 += __shfl_xor(a6, 32); a7 += __shfl_xor(a7, 32);

    float w0 = h ? a4 : a0;
    float w1 = h ? a5 : a1;
    float w2 = h ? a6 : a2;
    float w3 = h ? a7 : a3;
    int cw = cbase + h * 4;
    float4 b4 = *(const float4*)&bias[cw];
    float4 o;
    o.x = fmaxf(w0 + b4.x, 0.f);
    o.y = fmaxf(w1 + b4.y, 0.f);
    o.z = fmaxf(w2 + b4.z, 0.f);
    o.w = fmaxf(w3 + b4.w, 0.f);
    *(float4*)&out[(size_t)node * 256 + cw] = o;
}

extern "C" void kernel_launch(void* const* d_in, const int* in_sizes, int n_in,
                              void* d_out, int out_size, void* d_ws, size_t ws_size,
                              hipStream_t stream) {
    const float* x     = (const float*)d_in[0];
    const int*   erow  = (const int*)d_in[1];
    const int*   ecol  = (const int*)d_in[2];
    const float* evals = (const float*)d_in[3];
    const float* W     = (const float*)d_in[4];
    const float* bias  = (const float*)d_in[5];
    float* out = (float*)d_out;

    const int C = 256;
    const int N = in_sizes[0] / C;        // 100000
    const int E = in_sizes[1];            // 3200000
    const int NB = (N + 63) / 64;         // 1563 buckets of 64 rows

    // Workspace carve (256B aligned): 51.2 + 0.13 + 0.01 + 0.8 + 30.4 ~ 82.6MB
    // (proven fits in rounds 12-16).
    char* ws = (char*)d_ws;
    size_t off = 0;
    auto carve = [&](size_t bytes) -> void* {
        void* p = ws + off;
        off += (bytes + 255) & ~(size_t)255;
        return p;
    };
    unsigned short* Hbf = (unsigned short*)carve((size_t)N * C * 2);   // 51.2MB
    unsigned short* Wt  = (unsigned short*)carve((size_t)C * 256 * 2); // 0.13MB
    int*            gcur= (int*)carve((size_t)NB * 4);
    int2*           rinf= (int2*)carve((size_t)N * 8);                 // 0.8MB
    int2*           bin8= (int2*)carve((size_t)NB * CAP * 8);          // 30.4MB

    int nA3 = (E + CH_A3 - 1) / CH_A3;    // 391
    int gemmBlocks = (N + 63) / 64;       // 1563

    k_pre<<<257, 256, 0, stream>>>(W, Wt, gcur, NB);
    kD1<<<nA3 + gemmBlocks, 256, D1_SMEM, stream>>>(erow, ecol, evals, gcur,
                                                    bin8, E, NB, nA3,
                                                    x, Wt, Hbf, N);
    kB2<<<NB, 256, 0, stream>>>(bin8, gcur, rinf, N);
    k_agg<<<(N + 3) / 4, 256, 0, stream>>>(Hbf, rinf, (unsigned*)bin8, bias, out, N);
}